// Round 2
// baseline (373.076 us; speedup 1.0000x reference)
//
#include <hip/hip_runtime.h>

#define S 48
#define T 16
#define NTOT (2 * S * S * S * T) // 3,538,944
#define NC (NTOT / 4)            // 884,736 float4-chunks = 3456 * 256

__device__ __forceinline__ float4 ld4(const float* p) {
    return *reinterpret_cast<const float4*>(p);
}
__device__ __forceinline__ float4 f4sub(float4 a, float4 b) {
    return make_float4(a.x - b.x, a.y - b.y, a.z - b.z, a.w - b.w);
}
__device__ __forceinline__ float4 f4add(float4 a, float4 b) {
    return make_float4(a.x + b.x, a.y + b.y, a.z + b.z, a.w + b.w);
}
__device__ __forceinline__ float sum2(float4 a) {
    return a.x * a.x + a.y * a.y + a.z * a.z + a.w * a.w;
}

// torch.gradient d/d(axis) for 4 consecutive t at spatial coord i (all 4 share i).
__device__ __forceinline__ float4 d1s(const float* __restrict__ fc, int i, int N, int stride) {
    const int dl = (i > 0) ? -stride : 0;
    const int dr = (i < N - 1) ? stride : 0;
    const float w = (i > 0 && i < N - 1) ? 0.5f : 1.0f;
    float4 a = ld4(fc + dr), b = ld4(fc + dl);
    return make_float4((a.x - b.x) * w, (a.y - b.y) * w, (a.z - b.z) * w, (a.w - b.w) * w);
}

// composed gradient-of-gradient g(g(f)) along a spatial axis, 4 t at once.
//  i==0   : 0.5 f0 - f1 + 0.5 f2
//  i==1   : 0.5 f0 - 0.75 f1 + 0.25 f3
//  inner  : 0.25 f[i-2] - 0.5 f[i] + 0.25 f[i+2]
//  i==N-2 : 0.25 f[N-4] - 0.75 f[N-2] + 0.5 f[N-1]
//  i==N-1 : 0.5 f[N-3] - f[N-2] + 0.5 f[N-1]
__device__ __forceinline__ float4 d2c(const float* __restrict__ fc, int i, int N, int stride) {
    int j0, j1, j2;
    float c0, c1, c2;
    if (i == 0)          { j0 = 0;  j1 = 1;  j2 = 2; c0 = 0.5f;  c1 = -1.0f;  c2 = 0.5f;  }
    else if (i == 1)     { j0 = -1; j1 = 0;  j2 = 2; c0 = 0.5f;  c1 = -0.75f; c2 = 0.25f; }
    else if (i == N - 1) { j0 = -2; j1 = -1; j2 = 0; c0 = 0.5f;  c1 = -1.0f;  c2 = 0.5f;  }
    else if (i == N - 2) { j0 = -2; j1 = 0;  j2 = 1; c0 = 0.25f; c1 = -0.75f; c2 = 0.5f;  }
    else                 { j0 = -2; j1 = 0;  j2 = 2; c0 = 0.25f; c1 = -0.5f;  c2 = 0.25f; }
    float4 a = ld4(fc + j0 * stride), b = ld4(fc + j1 * stride), c = ld4(fc + j2 * stride);
    return make_float4(c0 * a.x + c1 * b.x + c2 * c.x,
                       c0 * a.y + c1 * b.y + c2 * c.y,
                       c0 * a.z + c1 * b.z + c2 * c.z,
                       c0 * a.w + c1 * b.w + c2 * c.w);
}

// d/dt for the 4 elements t0..t0+3 (row length T=16, t0 in {0,4,8,12}).
// c = already-loaded center vector at fc.
__device__ __forceinline__ float4 d1t(float4 c, const float* __restrict__ fc, int t0) {
    float4 r;
    r.x = (t0 == 0) ? (c.y - c.x) : (c.y - fc[-1]) * 0.5f;
    r.y = (c.z - c.x) * 0.5f;
    r.z = (c.w - c.y) * 0.5f;
    r.w = (t0 == 12) ? (c.w - c.z) : (fc[4] - c.z) * 0.5f;
    return r;
}

// Element strides:
//   V/F (B,S,S,S,3,T): t:1 ch:16 z:48 x:2304 y:110592  (ch0=Vy, ch1=Vx, ch2=Vz)
//   P/Y/X/X1/C (B,S,S,S,T): t:1 z:16 x:768 y:36864
__global__ __launch_bounds__(256) void fused_loss(
    const float* __restrict__ Cmat, const float* __restrict__ V,
    const float* __restrict__ P, const float* __restrict__ Xa,
    const float* __restrict__ X1a, const float* __restrict__ F,
    const float* __restrict__ Rep, const float* __restrict__ Xlast,
    const float* __restrict__ Y, float* __restrict__ ws)
{
    const float re = Rep[0];
    float am1 = 0.f, am2 = 0.f, aphy = 0.f, at1 = 0.f, at2 = 0.f;

    const int n4 = blockIdx.x * 256 + threadIdx.x; // exact grid: NC threads
    {
        const int sp = n4 >> 2;
        const int t0 = (n4 & 3) << 2;
        const int z  = sp % S;
        const int r1 = sp / S;
        const int x  = r1 % S;
        const int y  = (r1 / S) % S;

        // ---- elementwise losses (4 t at once) ----
        const int prow = sp * T + t0;
        const float4 yv  = ld4(Y + prow);
        const float4 x1v = ld4(X1a + prow);
        const float4 xv  = ld4(Xa + prow);
        const float4 cvv = ld4(Cmat + prow);
        am1 += sum2(f4sub(x1v, yv));
        am2 += sum2(f4sub(xv, yv));
        at2 += sum2(f4sub(cvv, yv));
        const float yp0 = (t0 == 0) ? Xlast[sp] : Y[prow - 1];
        const float4 pv = make_float4(yp0, yv.x, yv.y, yv.z);
        at1 += sum2(f4sub(pv, yv));

        // ---- physics loss ----
        const float* Pc = P + prow;
        const float4 dPdz = d1s(Pc, z, S, 16);
        const float4 dPdx = d1s(Pc, x, S, 768);
        const float4 dPdy = d1s(Pc, y, S, 36864);

        const int vbase = sp * 48 + t0;
        const float* Vyc = V + vbase;
        const float* Vxc = V + vbase + 16;
        const float* Vzc = V + vbase + 32;
        const float4 vy = ld4(Vyc), vx = ld4(Vxc), vz = ld4(Vzc);

        const float4 dVydt = d1t(vy, Vyc, t0);
        const float4 dVydz = d1s(Vyc, z, S, 48);
        const float4 dVydx = d1s(Vyc, x, S, 2304);
        const float4 dVydy = d1s(Vyc, y, S, 110592);
        const float4 lapVy = f4add(f4add(d2c(Vyc, z, S, 48), d2c(Vyc, x, S, 2304)),
                                   d2c(Vyc, y, S, 110592));

        const float4 dVxdt = d1t(vx, Vxc, t0);
        const float4 dVxdz = d1s(Vxc, z, S, 48);
        const float4 dVxdx = d1s(Vxc, x, S, 2304);
        const float4 dVxdy = d1s(Vxc, y, S, 110592);
        const float4 lapVx = f4add(f4add(d2c(Vxc, z, S, 48), d2c(Vxc, x, S, 2304)),
                                   d2c(Vxc, y, S, 110592));

        const float4 dVzdt = d1t(vz, Vzc, t0);
        const float4 dVzdz = d1s(Vzc, z, S, 48);
        const float4 dVzdx = d1s(Vzc, x, S, 2304);
        const float4 dVzdy = d1s(Vzc, y, S, 110592);
        const float4 lapVz = f4add(f4add(d2c(Vzc, z, S, 48), d2c(Vzc, x, S, 2304)),
                                   d2c(Vzc, y, S, 110592));

        const float4 fy = ld4(F + vbase), fx = ld4(F + vbase + 16), fz = ld4(F + vbase + 32);

        #define E_COMP(c)                                                                        \
        {                                                                                        \
            const float e1 = dVydt.c + (vx.c * dVydx.c + vy.c * dVydy.c + vz.c * dVydz.c + dPdy.c) - re * lapVy.c + fy.c; \
            const float e2 = dVxdt.c + (vx.c * dVxdx.c + vy.c * dVxdy.c + vz.c * dVxdz.c + dPdx.c) - re * lapVx.c + fx.c; \
            const float e3 = dVzdt.c + (vx.c * dVzdx.c + vy.c * dVzdy.c + vz.c * dVzdz.c + dPdz.c) - re * lapVz.c + fz.c; \
            const float e4 = dVxdx.c + dVydy.c + dVzdz.c;                                        \
            aphy += e1 * e1 + e2 * e2 + e3 * e3 + e4 * e4;                                       \
        }
        E_COMP(x) E_COMP(y) E_COMP(z) E_COMP(w)
        #undef E_COMP
    }

    // ---- reduction: wave shuffle -> LDS -> 5 atomics per block ----
    #pragma unroll
    for (int off = 32; off > 0; off >>= 1) {
        am1  += __shfl_down(am1, off);
        am2  += __shfl_down(am2, off);
        aphy += __shfl_down(aphy, off);
        at1  += __shfl_down(at1, off);
        at2  += __shfl_down(at2, off);
    }
    __shared__ float sred[4][5];
    const int lane = threadIdx.x & 63;
    const int wv   = threadIdx.x >> 6;
    if (lane == 0) {
        sred[wv][0] = am1; sred[wv][1] = am2; sred[wv][2] = aphy;
        sred[wv][3] = at1; sred[wv][4] = at2;
    }
    __syncthreads();
    if (threadIdx.x == 0) {
        float s0 = 0.f, s1 = 0.f, s2 = 0.f, s3 = 0.f, s4 = 0.f;
        #pragma unroll
        for (int w = 0; w < 4; ++w) {
            s0 += sred[w][0]; s1 += sred[w][1]; s2 += sred[w][2];
            s3 += sred[w][3]; s4 += sred[w][4];
        }
        atomicAdd(&ws[0], s0);
        atomicAdd(&ws[1], s1);
        atomicAdd(&ws[2], s2);
        atomicAdd(&ws[3], s3);
        atomicAdd(&ws[4], s4);
    }
}

__global__ void finalize_kernel(const float* __restrict__ ws, float* __restrict__ out) {
    const float invN = 1.0f / (float)NTOT;
    const float m1  = ws[0] * invN;
    const float m2  = ws[1] * invN;
    const float phy = ws[2] * invN;
    const float t1  = ws[3] * invN;
    const float t2  = ws[4] * invN;
    out[0] = m1;
    out[1] = m2;
    out[2] = phy;
    out[3] = (t1 < t2) ? (t2 - t1) : 0.0f;
}

extern "C" void kernel_launch(void* const* d_in, const int* in_sizes, int n_in,
                              void* d_out, int out_size, void* d_ws, size_t ws_size,
                              hipStream_t stream) {
    // setup_inputs order:
    // 0 C_all, 1 V_all, 2 P_all, 3 X_all, 4 X1_all, 5 F_all, 6 Re, 7 X_last,
    // 8 Y_data, 9 maskd0, 10 maskd1, 11 maskd2
    const float* Cmat  = (const float*)d_in[0];
    const float* V     = (const float*)d_in[1];
    const float* P     = (const float*)d_in[2];
    const float* Xa    = (const float*)d_in[3];
    const float* X1a   = (const float*)d_in[4];
    const float* F     = (const float*)d_in[5];
    const float* Rep   = (const float*)d_in[6];
    const float* Xlast = (const float*)d_in[7];
    const float* Y     = (const float*)d_in[8];

    float* ws  = (float*)d_ws;
    float* out = (float*)d_out;

    hipMemsetAsync(ws, 0, 5 * sizeof(float), stream);
    fused_loss<<<NC / 256, 256, 0, stream>>>(Cmat, V, P, Xa, X1a, F, Rep, Xlast, Y, ws);
    finalize_kernel<<<1, 1, 0, stream>>>(ws, out);
}

// Round 3
// 275.724 us; speedup vs baseline: 1.3531x; 1.3531x over previous
//
#include <hip/hip_runtime.h>

#define S 48
#define T 16
#define NTOT (2 * S * S * S * T) // 3,538,944
#define NC (NTOT / 4)            // 884,736 float4-chunks
#define NBLK 1152                // NC / (NBLK*256) == 3 exactly

__device__ __forceinline__ float4 ld4(const float* p) {
    return *reinterpret_cast<const float4*>(p);
}
__device__ __forceinline__ float4 operator-(float4 a, float4 b) {
    return make_float4(a.x - b.x, a.y - b.y, a.z - b.z, a.w - b.w);
}
__device__ __forceinline__ float4 operator+(float4 a, float4 b) {
    return make_float4(a.x + b.x, a.y + b.y, a.z + b.z, a.w + b.w);
}
__device__ __forceinline__ float4 operator*(float s, float4 a) {
    return make_float4(s * a.x, s * a.y, s * a.z, s * a.w);
}
__device__ __forceinline__ float4 operator*(float4 a, float4 b) {
    return make_float4(a.x * b.x, a.y * b.y, a.z * b.z, a.w * b.w);
}
__device__ __forceinline__ float sum2(float4 a) {
    return a.x * a.x + a.y * a.y + a.z * a.z + a.w * a.w;
}

// Per-axis stencil parameters (branchless; coefficients zero out clamped taps).
// g1 = w*(p1 - m1); g2 (= composed gradient-of-gradient) = cm2*m2 + cm1*m1 + cc*c + cp1*p1 + cp2*p2
struct AxisP {
    int om2, om1, op1, op2; // tap offsets in units of stride (clamped into range)
    float w, cm2, cm1, cc, cp1, cp2;
};
__device__ __forceinline__ AxisP axis_params(int i, int N) {
    AxisP a;
    a.om1 = (i > 0) ? -1 : 0;
    a.op1 = (i < N - 1) ? 1 : 0;
    a.om2 = (i >= 2) ? -2 : 0;
    a.op2 = (i < N - 2) ? 2 : 0;
    a.w   = (i > 0 && i < N - 1) ? 0.5f : 1.0f;
    a.cm2 = (i < 2) ? 0.0f : ((i == N - 1) ? 0.5f : 0.25f);
    a.cm1 = (i == 1) ? 0.5f : ((i == N - 1) ? -1.0f : 0.0f);
    a.cc  = (i == 0) ? 0.5f : (i == 1 || i == N - 2) ? -0.75f : (i == N - 1) ? 0.5f : -0.5f;
    a.cp1 = (i == 0) ? -1.0f : ((i == N - 2) ? 0.5f : 0.0f);
    a.cp2 = (i == 0) ? 0.5f : (i == 1) ? 0.25f : (i < N - 2) ? 0.25f : 0.0f;
    return a;
}

// first derivative + composed second derivative along one axis, 4 t at once
__device__ __forceinline__ void gboth(const float* __restrict__ fc, float4 c,
                                      const AxisP& a, int stride,
                                      float4& g1, float4& g2) {
    const float4 m2 = ld4(fc + a.om2 * stride);
    const float4 m1 = ld4(fc + a.om1 * stride);
    const float4 p1 = ld4(fc + a.op1 * stride);
    const float4 p2 = ld4(fc + a.op2 * stride);
    g1 = a.w * (p1 - m1);
    g2 = a.cm2 * m2 + a.cm1 * m1 + a.cc * c + a.cp1 * p1 + a.cp2 * p2;
}

// d/dt for elements t0..t0+3 (row length 16, t0 in {0,4,8,12}); c = center vector
__device__ __forceinline__ float4 d1t(float4 c, const float* __restrict__ fc, int t0) {
    float4 r;
    r.x = (t0 == 0) ? (c.y - c.x) : (c.y - fc[-1]) * 0.5f;
    r.y = (c.z - c.x) * 0.5f;
    r.z = (c.w - c.y) * 0.5f;
    r.w = (t0 == 12) ? (c.w - c.z) : (fc[4] - c.z) * 0.5f;
    return r;
}

// Element strides:
//   V/F (B,S,S,S,3,T): t:1 ch:16 z:48 x:2304 y:110592  (ch0=Vy, ch1=Vx, ch2=Vz)
//   P/Y/X/X1/C (B,S,S,S,T): t:1 z:16 x:768 y:36864
__global__ __launch_bounds__(256) void fused_loss(
    const float* __restrict__ Cmat, const float* __restrict__ V,
    const float* __restrict__ P, const float* __restrict__ Xa,
    const float* __restrict__ X1a, const float* __restrict__ F,
    const float* __restrict__ Rep, const float* __restrict__ Xlast,
    const float* __restrict__ Y, float* __restrict__ ws)
{
    const float re = Rep[0];
    float am1 = 0.f, am2 = 0.f, aphy = 0.f, at1 = 0.f, at2 = 0.f;

    for (int n4 = blockIdx.x * 256 + threadIdx.x; n4 < NC; n4 += NBLK * 256) {
        const int sp = n4 >> 2;
        const int t0 = (n4 & 3) << 2;
        const int z  = sp % S;
        const int r1 = sp / S;
        const int x  = r1 % S;
        const int y  = (r1 / S) % S;

        const AxisP az = axis_params(z, S);
        const AxisP ax = axis_params(x, S);
        const AxisP ay = axis_params(y, S);

        // ---- elementwise losses ----
        const int prow = sp * T + t0;
        const float4 yv  = ld4(Y + prow);
        const float4 x1v = ld4(X1a + prow);
        const float4 xv  = ld4(Xa + prow);
        const float4 cvv = ld4(Cmat + prow);
        am1 += sum2(x1v - yv);
        am2 += sum2(xv - yv);
        at2 += sum2(cvv - yv);
        const float yp0 = (t0 == 0) ? Xlast[sp] : Y[prow - 1];
        at1 += sum2(make_float4(yp0, yv.x, yv.y, yv.z) - yv);

        // ---- P first derivatives (clamped-offset, branchless) ----
        const float* Pc = P + prow;
        const float4 dPdz = az.w * (ld4(Pc + az.op1 * 16)    - ld4(Pc + az.om1 * 16));
        const float4 dPdx = ax.w * (ld4(Pc + ax.op1 * 768)   - ld4(Pc + ax.om1 * 768));
        const float4 dPdy = ay.w * (ld4(Pc + ay.op1 * 36864) - ld4(Pc + ay.om1 * 36864));

        // ---- velocity centers ----
        const int vbase = sp * 48 + t0;
        const float* Vyc = V + vbase;
        const float* Vxc = V + vbase + 16;
        const float* Vzc = V + vbase + 32;
        const float4 vy = ld4(Vyc), vx = ld4(Vxc), vz = ld4(Vzc);
        const float4 fy = ld4(F + vbase), fx = ld4(F + vbase + 16), fz = ld4(F + vbase + 32);

        float4 e4 = make_float4(0.f, 0.f, 0.f, 0.f);

        // ---- channel 0: Vy ----
        {
            float4 dz, lz, dx_, lx, dy_, ly;
            gboth(Vyc, vy, az, 48, dz, lz);
            gboth(Vyc, vy, ax, 2304, dx_, lx);
            gboth(Vyc, vy, ay, 110592, dy_, ly);
            const float4 dt = d1t(vy, Vyc, t0);
            const float4 lap = lz + lx + ly;
            const float4 e = dt + vx * dx_ + vy * dy_ + vz * dz + dPdy + (-re) * lap + fy;
            aphy += sum2(e);
            e4 = e4 + dy_;
        }
        // ---- channel 1: Vx ----
        {
            float4 dz, lz, dx_, lx, dy_, ly;
            gboth(Vxc, vx, az, 48, dz, lz);
            gboth(Vxc, vx, ax, 2304, dx_, lx);
            gboth(Vxc, vx, ay, 110592, dy_, ly);
            const float4 dt = d1t(vx, Vxc, t0);
            const float4 lap = lz + lx + ly;
            const float4 e = dt + vx * dx_ + vy * dy_ + vz * dz + dPdx + (-re) * lap + fx;
            aphy += sum2(e);
            e4 = e4 + dx_;
        }
        // ---- channel 2: Vz ----
        {
            float4 dz, lz, dx_, lx, dy_, ly;
            gboth(Vzc, vz, az, 48, dz, lz);
            gboth(Vzc, vz, ax, 2304, dx_, lx);
            gboth(Vzc, vz, ay, 110592, dy_, ly);
            const float4 dt = d1t(vz, Vzc, t0);
            const float4 lap = lz + lx + ly;
            const float4 e = dt + vx * dx_ + vy * dy_ + vz * dz + dPdz + (-re) * lap + fz;
            aphy += sum2(e);
            e4 = e4 + dz;
        }
        aphy += sum2(e4);
    }

    // ---- reduction: wave shuffle -> LDS -> 5 atomics per block ----
    #pragma unroll
    for (int off = 32; off > 0; off >>= 1) {
        am1  += __shfl_down(am1, off);
        am2  += __shfl_down(am2, off);
        aphy += __shfl_down(aphy, off);
        at1  += __shfl_down(at1, off);
        at2  += __shfl_down(at2, off);
    }
    __shared__ float sred[4][5];
    const int lane = threadIdx.x & 63;
    const int wv   = threadIdx.x >> 6;
    if (lane == 0) {
        sred[wv][0] = am1; sred[wv][1] = am2; sred[wv][2] = aphy;
        sred[wv][3] = at1; sred[wv][4] = at2;
    }
    __syncthreads();
    if (threadIdx.x == 0) {
        float s0 = 0.f, s1 = 0.f, s2 = 0.f, s3 = 0.f, s4 = 0.f;
        #pragma unroll
        for (int w = 0; w < 4; ++w) {
            s0 += sred[w][0]; s1 += sred[w][1]; s2 += sred[w][2];
            s3 += sred[w][3]; s4 += sred[w][4];
        }
        atomicAdd(&ws[0], s0);
        atomicAdd(&ws[1], s1);
        atomicAdd(&ws[2], s2);
        atomicAdd(&ws[3], s3);
        atomicAdd(&ws[4], s4);
    }
}

__global__ void finalize_kernel(const float* __restrict__ ws, float* __restrict__ out) {
    const float invN = 1.0f / (float)NTOT;
    const float m1  = ws[0] * invN;
    const float m2  = ws[1] * invN;
    const float phy = ws[2] * invN;
    const float t1  = ws[3] * invN;
    const float t2  = ws[4] * invN;
    out[0] = m1;
    out[1] = m2;
    out[2] = phy;
    out[3] = (t1 < t2) ? (t2 - t1) : 0.0f;
}

extern "C" void kernel_launch(void* const* d_in, const int* in_sizes, int n_in,
                              void* d_out, int out_size, void* d_ws, size_t ws_size,
                              hipStream_t stream) {
    // setup_inputs order:
    // 0 C_all, 1 V_all, 2 P_all, 3 X_all, 4 X1_all, 5 F_all, 6 Re, 7 X_last,
    // 8 Y_data, 9 maskd0, 10 maskd1, 11 maskd2
    const float* Cmat  = (const float*)d_in[0];
    const float* V     = (const float*)d_in[1];
    const float* P     = (const float*)d_in[2];
    const float* Xa    = (const float*)d_in[3];
    const float* X1a   = (const float*)d_in[4];
    const float* F     = (const float*)d_in[5];
    const float* Rep   = (const float*)d_in[6];
    const float* Xlast = (const float*)d_in[7];
    const float* Y     = (const float*)d_in[8];

    float* ws  = (float*)d_ws;
    float* out = (float*)d_out;

    hipMemsetAsync(ws, 0, 5 * sizeof(float), stream);
    fused_loss<<<NBLK, 256, 0, stream>>>(Cmat, V, P, Xa, X1a, F, Rep, Xlast, Y, ws);
    finalize_kernel<<<1, 1, 0, stream>>>(ws, out);
}